// Round 5
// baseline (808.655 us; speedup 1.0000x reference)
//
#include <hip/hip_runtime.h>
#include <cstdint>
#include <cstddef>

#define N_NODES 50000
#define M_PAD   50176   // 392 * 128
#define EPS_BN  1e-5f
#define NEG     0.2f

typedef __attribute__((ext_vector_type(8))) short bf16x8;
typedef __attribute__((ext_vector_type(4))) float f32x4;

// ---------- bf16 helpers ----------
static __device__ __forceinline__ ushort f2bf(float f) {
    unsigned u = __float_as_uint(f);
    unsigned r = (u + 0x7FFFu + ((u >> 16) & 1u)) >> 16;   // RNE
    return (ushort)r;
}
static __device__ __forceinline__ float bf2f(ushort b) {
    return __uint_as_float(((unsigned)b) << 16);
}
static __device__ __forceinline__ float leaky(float v) {
    return (v > 0.f) ? v : NEG * v;
}
// wavefront-scope fence: orders LDS write->cross-lane-read within a wave
static __device__ __forceinline__ void wave_fence() {
    __builtin_amdgcn_fence(__ATOMIC_ACQ_REL, "wavefront");
}

// ---------- input conversion: x fp32 [N,256] -> bf16 padded [M_PAD,256] ----------
__global__ void conv_x(const float* __restrict__ x, ushort* __restrict__ out) {
    const int i = blockIdx.x * 256 + threadIdx.x;
    const int e0 = i * 4;
    if (e0 >= M_PAD * 256) return;
    const int row = e0 >> 8;
    ushort4 o;
    if (row < N_NODES) {
        const float4 v = *(const float4*)&x[e0];
        o = make_ushort4(f2bf(v.x), f2bf(v.y), f2bf(v.z), f2bf(v.w));
    } else {
        o = make_ushort4(0, 0, 0, 0);
    }
    *(ushort4*)&out[e0] = o;
}

// ---------- weight convert + transpose: W fp32 [K,Nc] -> Wt bf16 [Nc,K] ----------
__global__ void convT(const float* __restrict__ W, ushort* __restrict__ Wt,
                      int K, int Nc) {
    const int i = blockIdx.x * 256 + threadIdx.x;
    if (i < K * Nc) {
        const int k = i / Nc, n = i - k * Nc;
        Wt[(size_t)n * K + k] = f2bf(W[i]);
    }
}

// ---------- wa precompute: wa[o*K+k] = sum_c W[k, hd*128+c] * a[hd][c] ----------
// o in [0,2H): o<H -> a_src head o ; o>=H -> a_dst head o-H
__global__ void wa_make(const float* __restrict__ W, const float* __restrict__ a_src,
                        const float* __restrict__ a_dst, float* __restrict__ wa,
                        int K, int H) {
    const int k = blockIdx.x, t = threadIdx.x, o = t >> 5;
    if (o < 2 * H) {
        const int hd = (o < H) ? o : (o - H);
        const float* av = (o < H) ? a_src : a_dst;
        const int c0 = (t & 31) * 4;
        const float4 wv = *(const float4*)&W[(size_t)k * (H * 128) + hd * 128 + c0];
        const float4 a4 = *(const float4*)&av[hd * 128 + c0];
        float p = wv.x * a4.x + wv.y * a4.y + wv.z * a4.z + wv.w * a4.w;
#pragma unroll
        for (int m = 16; m >= 1; m >>= 1) p += __shfl_xor(p, m, 32);
        if ((t & 31) == 0) wa[o * K + k] = p;
    }
}

// ---------- scores via x @ wa : s[n,h], d[n,h] ----------
template <int H, int K>
__global__ __launch_bounds__(256) void scores_gemm(
    const ushort* __restrict__ Xbf, const float* __restrict__ wa,
    float* __restrict__ s, float* __restrict__ d) {
    __shared__ float lwa[K * 2 * H];
    const int t = threadIdx.x;
    for (int i = t; i < K * 2 * H; i += 256) lwa[i] = wa[i];
    __syncthreads();
    const int w = t >> 6, lane = t & 63;
    const int n = blockIdx.x * 4 + w;
    float p[2 * H];
#pragma unroll
    for (int o = 0; o < 2 * H; ++o) p[o] = 0.f;
    if constexpr (K == 256) {
        const ushort4 xv = *(const ushort4*)&Xbf[(size_t)n * 256 + lane * 4];
        const float x0 = bf2f(xv.x), x1 = bf2f(xv.y), x2 = bf2f(xv.z), x3 = bf2f(xv.w);
#pragma unroll
        for (int o = 0; o < 2 * H; ++o) {
            const float4 wv = *(const float4*)&lwa[o * 256 + lane * 4];
            p[o] = x0 * wv.x + x1 * wv.y + x2 * wv.z + x3 * wv.w;
        }
    } else {
        const ushort2 xv = *(const ushort2*)&Xbf[(size_t)n * 128 + lane * 2];
        const float x0 = bf2f(xv.x), x1 = bf2f(xv.y);
#pragma unroll
        for (int o = 0; o < 2 * H; ++o) {
            const float2 wv = *(const float2*)&lwa[o * 128 + lane * 2];
            p[o] = x0 * wv.x + x1 * wv.y;
        }
    }
#pragma unroll
    for (int m = 1; m < 64; m <<= 1) {
#pragma unroll
        for (int o = 0; o < 2 * H; ++o) p[o] += __shfl_xor(p[o], m);
    }
    if (lane == 0) {
#pragma unroll
        for (int hh = 0; hh < H; ++hh) {
            s[n * H + hh] = p[hh];
            d[n * H + hh] = p[H + hh];
        }
    }
}

// ---------- MFMA GEMM: C[M_PAD,Nc] = A[M_PAD,K] * Bt[Nc,K]^T, all bf16, fp32 acc ----------
__global__ __launch_bounds__(256) void gemm_bf16(
    const ushort* __restrict__ A, const ushort* __restrict__ Bt,
    ushort* __restrict__ C, int K, int Nc) {
    __shared__ ushort As[128 * 32];
    __shared__ ushort Bs[64 * 32];
    const int t = threadIdx.x;
    const int wave = t >> 6, lane = t & 63;
    const int quad = lane >> 4, l16 = lane & 15;
    const int m0 = blockIdx.y * 128, n0 = blockIdx.x * 64;

    const int aRow = t >> 2, aCol = (t & 3) * 8;
    const ushort* aG0 = A + (size_t)(m0 + aRow) * K + aCol;
    const ushort* aG1 = A + (size_t)(m0 + 64 + aRow) * K + aCol;
    const ushort* bG  = Bt + (size_t)(n0 + aRow) * K + aCol;

    const int aOff0 = (wave * 32 + l16) * 32 + quad * 8;
    const int aOff1 = aOff0 + 16 * 32;
    const int bOff  = l16 * 32 + quad * 8;

    f32x4 acc[2][4] = {};
    for (int k0 = 0; k0 < K; k0 += 32) {
        const uint4 a0 = *(const uint4*)(aG0 + k0);
        const uint4 a1 = *(const uint4*)(aG1 + k0);
        const uint4 b0 = *(const uint4*)(bG + k0);
        __syncthreads();
        *(uint4*)&As[t * 8]        = a0;
        *(uint4*)&As[2048 + t * 8] = a1;
        *(uint4*)&Bs[t * 8]        = b0;
        __syncthreads();
        const bf16x8 af0 = *(const bf16x8*)&As[aOff0];
        const bf16x8 af1 = *(const bf16x8*)&As[aOff1];
#pragma unroll
        for (int nt = 0; nt < 4; ++nt) {
            const bf16x8 bf = *(const bf16x8*)&Bs[bOff + nt * 512];
            acc[0][nt] = __builtin_amdgcn_mfma_f32_16x16x32_bf16(af0, bf, acc[0][nt], 0, 0, 0);
            acc[1][nt] = __builtin_amdgcn_mfma_f32_16x16x32_bf16(af1, bf, acc[1][nt], 0, 0, 0);
        }
    }
    const int rowBase = m0 + wave * 32;
#pragma unroll
    for (int mt = 0; mt < 2; ++mt) {
#pragma unroll
        for (int nt = 0; nt < 4; ++nt) {
            const int col = n0 + nt * 16 + l16;
#pragma unroll
            for (int r = 0; r < 4; ++r) {
                const int row = rowBase + mt * 16 + quad * 4 + r;
                C[(size_t)row * Nc + col] = f2bf(acc[mt][nt][r]);
            }
        }
    }
}

// ---------- CSR build ----------
__global__ void edge_hist(const int* __restrict__ ei, int E, int* __restrict__ cnt) {
    const int k = blockIdx.x * blockDim.x + threadIdx.x;
    const int ET = E + N_NODES;
    if (k < ET) {
        const int dstn = (k < E) ? ei[E + k] : (k - E);
        atomicAdd(&cnt[dstn], 1);
    }
}

__global__ __launch_bounds__(256) void scan_phase1(
    const int* __restrict__ cnt, int* __restrict__ incl,
    int* __restrict__ bsum, int n) {
    __shared__ int sh[256];
    const int b = blockIdx.x, t = threadIdx.x;
    const int i0 = b * 1024 + t * 4;
    int v[4]; int sum = 0;
#pragma unroll
    for (int k = 0; k < 4; ++k) {
        v[k] = (i0 + k < n) ? cnt[i0 + k] : 0;
        sum += v[k];
    }
    sh[t] = sum;
    __syncthreads();
    for (int off = 1; off < 256; off <<= 1) {
        const int a = (t >= off) ? sh[t - off] : 0;
        __syncthreads();
        sh[t] += a;
        __syncthreads();
    }
    int run = sh[t] - sum;
#pragma unroll
    for (int k = 0; k < 4; ++k) {
        run += v[k];
        if (i0 + k < n) incl[i0 + k] = run;
    }
    if (t == 255) bsum[b] = sh[255];
}

__global__ void scan_phase2(int* __restrict__ bsum, int nb) {
    if (threadIdx.x == 0) {
        int run = 0;
        for (int i = 0; i < nb; ++i) { const int v = bsum[i]; bsum[i] = run; run += v; }
    }
}

__global__ void scan_phase3(const int* __restrict__ incl, const int* __restrict__ boffs,
                            int* __restrict__ rowptr, int* __restrict__ cursor, int n) {
    const int i = blockIdx.x * 256 + threadIdx.x;
    if (i < n) {
        rowptr[i + 1] = incl[i] + boffs[i >> 10];
        cursor[i] = (i == 0) ? 0 : (incl[i - 1] + boffs[(i - 1) >> 10]);
    }
    if (i == 0) rowptr[0] = 0;
}

// col order within a row is irrelevant: max/sum are order-independent.
__global__ void edge_scatter(const int* __restrict__ ei, int E,
                             int* __restrict__ cursor, int* __restrict__ col) {
    const int k = blockIdx.x * blockDim.x + threadIdx.x;
    const int ET = E + N_NODES;
    if (k < ET) {
        const int srcn = (k < E) ? ei[k] : (k - E);
        const int dstn = (k < E) ? ei[E + k] : (k - E);
        const int p = atomicAdd(&cursor[dstn], 1);
        col[p] = srcn;
    }
}

// ---------- aggregation H=4: 4 waves/block, one node per wave, private LDS ----------
__global__ __launch_bounds__(256, 8) void aggregate4(
    const ushort* __restrict__ h, const float* __restrict__ s,
    const float* __restrict__ d, const int* __restrict__ rowptr,
    const int* __restrict__ col, const float* __restrict__ bias,
    float* __restrict__ y) {
    __shared__ int   ls[4][128];
    __shared__ float lex[4][512];
    const int t = threadIdx.x, w = t >> 6, lane = t & 63;
    const int n = blockIdx.x * 4 + w;
    const int head = lane >> 4;
    const int rs = rowptr[n], re = rowptr[n + 1], deg = re - rs;
    const float4 dn = *(const float4*)&d[n * 4];
    int* lsw = ls[w];
    float* lexw = lex[w];

    float acc[8];
#pragma unroll
    for (int k = 0; k < 8; ++k) acc[k] = 0.f;
    float4 dsum = make_float4(0.f, 0.f, 0.f, 0.f);
    float4 mx = make_float4(-3.4e38f, -3.4e38f, -3.4e38f, -3.4e38f);

    if (deg <= 128) {
        // single s-read: e -> LDS, running max
#pragma unroll
        for (int it = 0; it < 2; ++it) {
            const int jj = lane + it * 64;
            if (jj < deg) {
                const int sn = col[rs + jj];
                lsw[jj] = sn;
                const float4 sv = *(const float4*)&s[sn * 4];
                float4 e;
                e.x = leaky(sv.x + dn.x); e.y = leaky(sv.y + dn.y);
                e.z = leaky(sv.z + dn.z); e.w = leaky(sv.w + dn.w);
                *(float4*)&lexw[jj * 4] = e;
                mx.x = fmaxf(mx.x, e.x); mx.y = fmaxf(mx.y, e.y);
                mx.z = fmaxf(mx.z, e.z); mx.w = fmaxf(mx.w, e.w);
            }
        }
#pragma unroll
        for (int off = 1; off < 64; off <<= 1) {
            mx.x = fmaxf(mx.x, __shfl_xor(mx.x, off));
            mx.y = fmaxf(mx.y, __shfl_xor(mx.y, off));
            mx.z = fmaxf(mx.z, __shfl_xor(mx.z, off));
            mx.w = fmaxf(mx.w, __shfl_xor(mx.w, off));
        }
        // exp in place (same-lane addresses) + denominator partial
#pragma unroll
        for (int it = 0; it < 2; ++it) {
            const int jj = lane + it * 64;
            if (jj < deg) {
                float4 e = *(const float4*)&lexw[jj * 4];
                e.x = __expf(e.x - mx.x); e.y = __expf(e.y - mx.y);
                e.z = __expf(e.z - mx.z); e.w = __expf(e.w - mx.w);
                *(float4*)&lexw[jj * 4] = e;
                dsum.x += e.x; dsum.y += e.y; dsum.z += e.z; dsum.w += e.w;
            }
        }
        wave_fence();
        for (int jj = 0; jj < deg; ++jj) {
            const int sn = lsw[jj];
            const float exh = lexw[jj * 4 + head];
            const bf16x8 hv = *(const bf16x8*)&h[(size_t)sn * 512 + lane * 8];
#pragma unroll
            for (int k = 0; k < 8; ++k) acc[k] = fmaf(exh, bf2f((ushort)hv[k]), acc[k]);
        }
    } else {
        // rare fallback: strided max pass, then chunks of 128 with recompute
        for (int j = rs + lane; j < re; j += 64) {
            const float4 sv = *(const float4*)&s[col[j] * 4];
            mx.x = fmaxf(mx.x, leaky(sv.x + dn.x));
            mx.y = fmaxf(mx.y, leaky(sv.y + dn.y));
            mx.z = fmaxf(mx.z, leaky(sv.z + dn.z));
            mx.w = fmaxf(mx.w, leaky(sv.w + dn.w));
        }
#pragma unroll
        for (int off = 1; off < 64; off <<= 1) {
            mx.x = fmaxf(mx.x, __shfl_xor(mx.x, off));
            mx.y = fmaxf(mx.y, __shfl_xor(mx.y, off));
            mx.z = fmaxf(mx.z, __shfl_xor(mx.z, off));
            mx.w = fmaxf(mx.w, __shfl_xor(mx.w, off));
        }
        for (int c0 = rs; c0 < re; c0 += 128) {
            const int cend = min(re, c0 + 128);
#pragma unroll
            for (int it = 0; it < 2; ++it) {
                const int j = c0 + lane + it * 64;
                if (j < cend) {
                    const int sn = col[j];
                    const int jj = j - c0;
                    lsw[jj] = sn;
                    const float4 sv = *(const float4*)&s[sn * 4];
                    float4 e;
                    e.x = __expf(leaky(sv.x + dn.x) - mx.x);
                    e.y = __expf(leaky(sv.y + dn.y) - mx.y);
                    e.z = __expf(leaky(sv.z + dn.z) - mx.z);
                    e.w = __expf(leaky(sv.w + dn.w) - mx.w);
                    *(float4*)&lexw[jj * 4] = e;
                    dsum.x += e.x; dsum.y += e.y; dsum.z += e.z; dsum.w += e.w;
                }
            }
            wave_fence();
            const int cnum = cend - c0;
            for (int jj = 0; jj < cnum; ++jj) {
                const int sn = lsw[jj];
                const float exh = lexw[jj * 4 + head];
                const bf16x8 hv = *(const bf16x8*)&h[(size_t)sn * 512 + lane * 8];
#pragma unroll
                for (int k = 0; k < 8; ++k) acc[k] = fmaf(exh, bf2f((ushort)hv[k]), acc[k]);
            }
            wave_fence();
        }
    }

#pragma unroll
    for (int off = 1; off < 64; off <<= 1) {
        dsum.x += __shfl_xor(dsum.x, off);
        dsum.y += __shfl_xor(dsum.y, off);
        dsum.z += __shfl_xor(dsum.z, off);
        dsum.w += __shfl_xor(dsum.w, off);
    }
    const float dsel = (head == 0) ? dsum.x : (head == 1) ? dsum.y
                     : (head == 2) ? dsum.z : dsum.w;
    const float inv = 1.f / (dsel + 1e-16f);
    // reuse lexw as the 512-float head-merge buffer
    wave_fence();
#pragma unroll
    for (int k = 0; k < 8; ++k) lexw[lane * 8 + k] = acc[k] * inv;
    wave_fence();
    {
        const int c = lane * 2;
        const float m0 = 0.25f * (lexw[c] + lexw[128 + c] + lexw[256 + c] + lexw[384 + c]);
        const float m1 = 0.25f * (lexw[c + 1] + lexw[128 + c + 1] + lexw[256 + c + 1] + lexw[384 + c + 1]);
        float2 o = make_float2(m0 + bias[c], m1 + bias[c + 1]);
        *(float2*)&y[(size_t)n * 128 + c] = o;
    }
}

// ---------- aggregation H=1: 4 waves/block, one node per wave ----------
__global__ __launch_bounds__(256, 8) void aggregate1(
    const ushort* __restrict__ h, const float* __restrict__ s,
    const float* __restrict__ d, const int* __restrict__ rowptr,
    const int* __restrict__ col, const float* __restrict__ bias,
    float* __restrict__ y) {
    __shared__ int   ls[4][128];
    __shared__ float lex[4][128];
    const int t = threadIdx.x, w = t >> 6, lane = t & 63;
    const int n = blockIdx.x * 4 + w;
    const int rs = rowptr[n], re = rowptr[n + 1], deg = re - rs;
    const float dn = d[n];
    int* lsw = ls[w];
    float* lexw = lex[w];

    float acc0 = 0.f, acc1 = 0.f, dsum = 0.f;
    float mx = -3.4e38f;

    if (deg <= 128) {
#pragma unroll
        for (int it = 0; it < 2; ++it) {
            const int jj = lane + it * 64;
            if (jj < deg) {
                const int sn = col[rs + jj];
                lsw[jj] = sn;
                const float e = leaky(s[sn] + dn);
                lexw[jj] = e;
                mx = fmaxf(mx, e);
            }
        }
#pragma unroll
        for (int off = 1; off < 64; off <<= 1) mx = fmaxf(mx, __shfl_xor(mx, off));
#pragma unroll
        for (int it = 0; it < 2; ++it) {
            const int jj = lane + it * 64;
            if (jj < deg) {
                const float ex = __expf(lexw[jj] - mx);
                lexw[jj] = ex;
                dsum += ex;
            }
        }
        wave_fence();
        for (int jj = 0; jj < deg; ++jj) {
            const int sn = lsw[jj];
            const float ex = lexw[jj];
            const ushort2 hv = *(const ushort2*)&h[(size_t)sn * 128 + lane * 2];
            acc0 = fmaf(ex, bf2f(hv.x), acc0);
            acc1 = fmaf(ex, bf2f(hv.y), acc1);
        }
    } else {
        for (int j = rs + lane; j < re; j += 64) {
            mx = fmaxf(mx, leaky(s[col[j]] + dn));
        }
#pragma unroll
        for (int off = 1; off < 64; off <<= 1) mx = fmaxf(mx, __shfl_xor(mx, off));
        for (int c0 = rs; c0 < re; c0 += 128) {
            const int cend = min(re, c0 + 128);
#pragma unroll
            for (int it = 0; it < 2; ++it) {
                const int j = c0 + lane + it * 64;
                if (j < cend) {
                    const int sn = col[j];
                    const int jj = j - c0;
                    lsw[jj] = sn;
                    const float ex = __expf(leaky(s[sn] + dn) - mx);
                    lexw[jj] = ex;
                    dsum += ex;
                }
            }
            wave_fence();
            const int cnum = cend - c0;
            for (int jj = 0; jj < cnum; ++jj) {
                const int sn = lsw[jj];
                const float ex = lexw[jj];
                const ushort2 hv = *(const ushort2*)&h[(size_t)sn * 128 + lane * 2];
                acc0 = fmaf(ex, bf2f(hv.x), acc0);
                acc1 = fmaf(ex, bf2f(hv.y), acc1);
            }
            wave_fence();
        }
    }
#pragma unroll
    for (int off = 1; off < 64; off <<= 1) dsum += __shfl_xor(dsum, off);
    const float inv = 1.f / (dsum + 1e-16f);
    const int c = lane * 2;
    float2 o = make_float2(acc0 * inv + bias[c], acc1 * inv + bias[c + 1]);
    *(float2*)&y[(size_t)n * 128 + c] = o;
}

// ---------- BatchNorm ----------
__global__ __launch_bounds__(256) void bn_stats1(
    const float* __restrict__ y, float* __restrict__ partial, int nblocks) {
    const int b = blockIdx.x, t = threadIdx.x;
    const int c = t & 127;
    float sum = 0.f, sq = 0.f;
    for (int r = b * 2 + (t >> 7); r < N_NODES; r += nblocks * 2) {
        const float v = y[(size_t)r * 128 + c];
        sum += v;
        sq += v * v;
    }
    __shared__ float s1[256], s2[256];
    s1[t] = sum; s2[t] = sq;
    __syncthreads();
    if (t < 128) {
        partial[(size_t)b * 256 + c] = s1[t] + s1[t + 128];
        partial[(size_t)b * 256 + 128 + c] = s2[t] + s2[t + 128];
    }
}

__global__ __launch_bounds__(128) void bn_stats2(
    const float* __restrict__ partial, int nblocks,
    const float* __restrict__ gamma, const float* __restrict__ beta,
    float* __restrict__ stats) {
    const int c = threadIdx.x;
    float S = 0.f, Q = 0.f;
    for (int b = 0; b < nblocks; ++b) {
        S += partial[(size_t)b * 256 + c];
        Q += partial[(size_t)b * 256 + 128 + c];
    }
    const float mu = S / (float)N_NODES;
    const float var = Q / (float)N_NODES - mu * mu;
    const float sc = gamma[c] * rsqrtf(var + EPS_BN);
    stats[c] = sc;
    stats[128 + c] = beta[c] - mu * sc;
}

__global__ void bn_apply_bf16(const float* __restrict__ y,
                              const float* __restrict__ stats,
                              ushort* __restrict__ out) {
    const int i = blockIdx.x * 256 + threadIdx.x;
    const int e0 = i * 4;
    if (e0 >= M_PAD * 128) return;
    const int row = e0 >> 7;
    ushort4 o;
    if (row < N_NODES) {
        const float4 v = *(const float4*)&y[e0];
        const int c = e0 & 127;
        const float a = fmaxf(v.x * stats[c]     + stats[128 + c],     0.f);
        const float b = fmaxf(v.y * stats[c + 1] + stats[128 + c + 1], 0.f);
        const float cc = fmaxf(v.z * stats[c + 2] + stats[128 + c + 2], 0.f);
        const float d = fmaxf(v.w * stats[c + 3] + stats[128 + c + 3], 0.f);
        o = make_ushort4(f2bf(a), f2bf(b), f2bf(cc), f2bf(d));
    } else {
        o = make_ushort4(0, 0, 0, 0);
    }
    *(ushort4*)&out[e0] = o;
}

__global__ void bn_apply_out(const float* __restrict__ y,
                             const float* __restrict__ stats,
                             float* __restrict__ out) {
    const int i = blockIdx.x * blockDim.x + threadIdx.x;
    if (i < N_NODES * 128) {
        const int c = i & 127;
        out[i] = y[i] * stats[c] + stats[128 + c];
    }
}

// ---------- launch ----------
extern "C" void kernel_launch(void* const* d_in, const int* in_sizes, int n_in,
                              void* d_out, int out_size, void* d_ws, size_t ws_size,
                              hipStream_t stream) {
    const float* x = (const float*)d_in[0];
    const int* ei = (const int*)d_in[1];
    const int E = in_sizes[1] / 2;
    const int ET = E + N_NODES;

    const float* W[3]    = {(const float*)d_in[2], (const float*)d_in[8],  (const float*)d_in[14]};
    const float* ASRC[3] = {(const float*)d_in[3], (const float*)d_in[9],  (const float*)d_in[15]};
    const float* ADST[3] = {(const float*)d_in[4], (const float*)d_in[10], (const float*)d_in[16]};
    const float* BIAS[3] = {(const float*)d_in[5], (const float*)d_in[11], (const float*)d_in[17]};
    const float* GAM[3]  = {(const float*)d_in[6], (const float*)d_in[12], (const float*)d_in[18]};
    const float* BET[3]  = {(const float*)d_in[7], (const float*)d_in[13], (const float*)d_in[19]};

    char* base = (char*)d_ws;
    auto alloc = [&](size_t bytes) {
        char* p = base;
        base += (bytes + 255) & ~(size_t)255;
        return p;
    };
    ushort* hbf    = (ushort*)alloc((size_t)M_PAD * 512 * 2);
    ushort* Xbf    = (ushort*)alloc((size_t)M_PAD * 256 * 2);
    ushort* Wt     = (ushort*)alloc((size_t)512 * 256 * 2);
    float*  y      = (float*)alloc((size_t)N_NODES * 128 * 4);
    float*  s      = (float*)alloc((size_t)N_NODES * 4 * 4);
    float*  dsc    = (float*)alloc((size_t)N_NODES * 4 * 4);
    int*    rowptr = (int*)alloc((size_t)(N_NODES + 1) * 4);
    int*    col    = (int*)alloc((size_t)ET * 4);
    int*    cnt    = (int*)alloc((size_t)N_NODES * 4);          // reused as cursor
    int*    incl   = (int*)alloc((size_t)N_NODES * 4);
    int*    bsum   = (int*)alloc((size_t)64 * 4);
    float*  partial = (float*)alloc((size_t)256 * 256 * 4);
    float*  stats   = (float*)alloc((size_t)256 * 4);
    float*  wa0     = (float*)alloc((size_t)256 * 8 * 4);
    float*  wa1     = (float*)alloc((size_t)128 * 8 * 4);
    float*  wa2     = (float*)alloc((size_t)128 * 2 * 4);
    if ((size_t)(base - (char*)d_ws) > ws_size) return;

    const int eb = (ET + 255) / 256;
    const int nScanB = (N_NODES + 1023) / 1024;

    // --- CSR build ---
    hipMemsetAsync(cnt, 0, (size_t)N_NODES * 4, stream);
    edge_hist<<<eb, 256, 0, stream>>>(ei, E, cnt);
    scan_phase1<<<nScanB, 256, 0, stream>>>(cnt, incl, bsum, N_NODES);
    scan_phase2<<<1, 64, 0, stream>>>(bsum, nScanB);
    scan_phase3<<<(N_NODES + 255) / 256, 256, 0, stream>>>(incl, bsum, rowptr, cnt, N_NODES);
    edge_scatter<<<eb, 256, 0, stream>>>(ei, E, cnt, col);

    // --- per-layer score projections wa = W^T a (tiny) ---
    wa_make<<<256, 256, 0, stream>>>(W[0], ASRC[0], ADST[0], wa0, 256, 4);
    wa_make<<<128, 256, 0, stream>>>(W[1], ASRC[1], ADST[1], wa1, 128, 4);
    wa_make<<<128, 256, 0, stream>>>(W[2], ASRC[2], ADST[2], wa2, 128, 1);

    // --- layer-0 input to bf16 (padded) ---
    conv_x<<<(M_PAD * 256 / 4 + 255) / 256, 256, 0, stream>>>(x, Xbf);

    const int Hs[3]  = {4, 4, 1};
    const int Kin[3] = {256, 128, 128};
    float* WA[3] = {wa0, wa1, wa2};

    for (int L = 0; L < 3; ++L) {
        const int H = Hs[L], K = Kin[L], Nc = H * 128;

        convT<<<(K * Nc + 255) / 256, 256, 0, stream>>>(W[L], Wt, K, Nc);
        dim3 ggrid(Nc / 64, M_PAD / 128);
        gemm_bf16<<<ggrid, 256, 0, stream>>>(Xbf, Wt, hbf, K, Nc);

        if (H == 4) {
            if (K == 256) scores_gemm<4, 256><<<N_NODES / 4, 256, 0, stream>>>(Xbf, WA[L], s, dsc);
            else          scores_gemm<4, 128><<<N_NODES / 4, 256, 0, stream>>>(Xbf, WA[L], s, dsc);
            aggregate4<<<N_NODES / 4, 256, 0, stream>>>(hbf, s, dsc, rowptr, col, BIAS[L], y);
        } else {
            scores_gemm<1, 128><<<N_NODES / 4, 256, 0, stream>>>(Xbf, WA[L], s, dsc);
            aggregate1<<<N_NODES / 4, 256, 0, stream>>>(hbf, s, dsc, rowptr, col, BIAS[L], y);
        }

        bn_stats1<<<256, 256, 0, stream>>>(y, partial, 256);
        bn_stats2<<<1, 128, 0, stream>>>(partial, 256, GAM[L], BET[L], stats);

        if (L < 2) {
            bn_apply_bf16<<<(M_PAD * 128 / 4 + 255) / 256, 256, 0, stream>>>(y, stats, Xbf);
        } else {
            bn_apply_out<<<(N_NODES * 128 + 255) / 256, 256, 0, stream>>>(y, stats, (float*)d_out);
        }
    }
}

// Round 6
// 640.330 us; speedup vs baseline: 1.2629x; 1.2629x over previous
//
#include <hip/hip_runtime.h>
#include <cstdint>
#include <cstddef>

#define N_NODES 50000
#define M_PAD   50176   // 392 * 128
#define EPS_BN  1e-5f
#define NEG     0.2f

typedef __attribute__((ext_vector_type(8))) short bf16x8;
typedef __attribute__((ext_vector_type(4))) float f32x4;

// ---------- bf16 helpers ----------
static __device__ __forceinline__ ushort f2bf(float f) {
    unsigned u = __float_as_uint(f);
    unsigned r = (u + 0x7FFFu + ((u >> 16) & 1u)) >> 16;   // RNE
    return (ushort)r;
}
static __device__ __forceinline__ float bf2f(ushort b) {
    return __uint_as_float(((unsigned)b) << 16);
}
static __device__ __forceinline__ float leaky(float v) {
    return (v > 0.f) ? v : NEG * v;
}
static __device__ __forceinline__ void wave_fence() {
    __builtin_amdgcn_fence(__ATOMIC_ACQ_REL, "wavefront");
}

// ---------- prep: conv_x (fp32->bf16 padded) + all 3 weight transposes ----------
// weights: W0 256x512 -> Wt0[512][256]; W1 128x512 -> Wt1[512][128]; W2 128x128 -> Wt2[128][128]
__global__ __launch_bounds__(256) void prep(
    const float* __restrict__ x, ushort* __restrict__ Xbf,
    const float* __restrict__ W0, const float* __restrict__ W1,
    const float* __restrict__ W2, ushort* __restrict__ Wt0,
    ushort* __restrict__ Wt1, ushort* __restrict__ Wt2) {
    const int gi = blockIdx.x * 256 + threadIdx.x;
    // part 1: x conversion, 4 elems/thread
    const int e0 = gi * 4;
    if (e0 < M_PAD * 256) {
        const int row = e0 >> 8;
        ushort4 o;
        if (row < N_NODES) {
            const float4 v = *(const float4*)&x[e0];
            o = make_ushort4(f2bf(v.x), f2bf(v.y), f2bf(v.z), f2bf(v.w));
        } else {
            o = make_ushort4(0, 0, 0, 0);
        }
        *(ushort4*)&Xbf[e0] = o;
    }
    // part 2: weight transpose (total 212992 elems, first 832 blocks)
    if (gi < 131072) {                       // W0
        const int k = gi >> 9, n = gi & 511;
        Wt0[(size_t)n * 256 + k] = f2bf(W0[gi]);
    } else if (gi < 196608) {                // W1
        const int j = gi - 131072;
        const int k = j >> 9, n = j & 511;
        Wt1[(size_t)n * 128 + k] = f2bf(W1[j]);
    } else if (gi < 212992) {                // W2
        const int j = gi - 196608;
        const int k = j >> 7, n = j & 127;
        Wt2[(size_t)n * 128 + k] = f2bf(W2[j]);
    }
}

// ---------- MFMA GEMM from bf16 A: C[M_PAD,Nc] = A * Bt^T ----------
__global__ __launch_bounds__(256) void gemm_bf(
    const ushort* __restrict__ A, const ushort* __restrict__ Bt,
    ushort* __restrict__ C, int K, int Nc) {
    __shared__ ushort As[128 * 32];
    __shared__ ushort Bs[64 * 32];
    const int t = threadIdx.x;
    const int wave = t >> 6, lane = t & 63;
    const int quad = lane >> 4, l16 = lane & 15;
    const int m0 = blockIdx.y * 128, n0 = blockIdx.x * 64;

    const int aRow = t >> 2, aCol = (t & 3) * 8;
    const ushort* aG0 = A + (size_t)(m0 + aRow) * K + aCol;
    const ushort* aG1 = A + (size_t)(m0 + 64 + aRow) * K + aCol;
    const ushort* bG  = Bt + (size_t)(n0 + aRow) * K + aCol;

    const int aOff0 = (wave * 32 + l16) * 32 + quad * 8;
    const int aOff1 = aOff0 + 16 * 32;
    const int bOff  = l16 * 32 + quad * 8;

    f32x4 acc[2][4] = {};
    for (int k0 = 0; k0 < K; k0 += 32) {
        const uint4 a0 = *(const uint4*)(aG0 + k0);
        const uint4 a1 = *(const uint4*)(aG1 + k0);
        const uint4 b0 = *(const uint4*)(bG + k0);
        __syncthreads();
        *(uint4*)&As[t * 8]        = a0;
        *(uint4*)&As[2048 + t * 8] = a1;
        *(uint4*)&Bs[t * 8]        = b0;
        __syncthreads();
        const bf16x8 af0 = *(const bf16x8*)&As[aOff0];
        const bf16x8 af1 = *(const bf16x8*)&As[aOff1];
#pragma unroll
        for (int nt = 0; nt < 4; ++nt) {
            const bf16x8 bf = *(const bf16x8*)&Bs[bOff + nt * 512];
            acc[0][nt] = __builtin_amdgcn_mfma_f32_16x16x32_bf16(af0, bf, acc[0][nt], 0, 0, 0);
            acc[1][nt] = __builtin_amdgcn_mfma_f32_16x16x32_bf16(af1, bf, acc[1][nt], 0, 0, 0);
        }
    }
    const int rowBase = m0 + wave * 32;
#pragma unroll
    for (int mt = 0; mt < 2; ++mt) {
#pragma unroll
        for (int nt = 0; nt < 4; ++nt) {
            const int col = n0 + nt * 16 + l16;
#pragma unroll
            for (int r = 0; r < 4; ++r) {
                const int row = rowBase + mt * 16 + quad * 4 + r;
                C[(size_t)row * Nc + col] = f2bf(acc[mt][nt][r]);
            }
        }
    }
}

// ---------- MFMA GEMM with fused BN+ReLU prologue: A = bn_relu(y) , K=128 ----------
__global__ __launch_bounds__(256) void gemm_bn(
    const float* __restrict__ Y, const float* __restrict__ stats,
    const ushort* __restrict__ Bt, ushort* __restrict__ C, int Nc) {
    constexpr int K = 128;
    __shared__ ushort As[128 * 32];
    __shared__ ushort Bs[64 * 32];
    __shared__ float lsc[128], lsh[128];
    const int t = threadIdx.x;
    if (t < 128) { lsc[t] = stats[t]; lsh[t] = stats[128 + t]; }
    const int wave = t >> 6, lane = t & 63;
    const int quad = lane >> 4, l16 = lane & 15;
    const int m0 = blockIdx.y * 128, n0 = blockIdx.x * 64;

    const int aRow = t >> 2, aCol = (t & 3) * 8;
    const float* yG0 = Y + (size_t)(m0 + aRow) * K + aCol;
    const float* yG1 = Y + (size_t)(m0 + 64 + aRow) * K + aCol;
    const ushort* bG = Bt + (size_t)(n0 + aRow) * K + aCol;

    const int aOff0 = (wave * 32 + l16) * 32 + quad * 8;
    const int aOff1 = aOff0 + 16 * 32;
    const int bOff  = l16 * 32 + quad * 8;

    f32x4 acc[2][4] = {};
    for (int k0 = 0; k0 < K; k0 += 32) {
        const float4 a00 = *(const float4*)(yG0 + k0);
        const float4 a01 = *(const float4*)(yG0 + k0 + 4);
        const float4 a10 = *(const float4*)(yG1 + k0);
        const float4 a11 = *(const float4*)(yG1 + k0 + 4);
        const uint4 b0 = *(const uint4*)(bG + k0);
        __syncthreads();   // lsc/lsh visible after this barrier
        const int c = aCol + k0;
        ushort u0[8], u1[8];
        u0[0] = f2bf(fmaxf(a00.x * lsc[c+0] + lsh[c+0], 0.f));
        u0[1] = f2bf(fmaxf(a00.y * lsc[c+1] + lsh[c+1], 0.f));
        u0[2] = f2bf(fmaxf(a00.z * lsc[c+2] + lsh[c+2], 0.f));
        u0[3] = f2bf(fmaxf(a00.w * lsc[c+3] + lsh[c+3], 0.f));
        u0[4] = f2bf(fmaxf(a01.x * lsc[c+4] + lsh[c+4], 0.f));
        u0[5] = f2bf(fmaxf(a01.y * lsc[c+5] + lsh[c+5], 0.f));
        u0[6] = f2bf(fmaxf(a01.z * lsc[c+6] + lsh[c+6], 0.f));
        u0[7] = f2bf(fmaxf(a01.w * lsc[c+7] + lsh[c+7], 0.f));
        u1[0] = f2bf(fmaxf(a10.x * lsc[c+0] + lsh[c+0], 0.f));
        u1[1] = f2bf(fmaxf(a10.y * lsc[c+1] + lsh[c+1], 0.f));
        u1[2] = f2bf(fmaxf(a10.z * lsc[c+2] + lsh[c+2], 0.f));
        u1[3] = f2bf(fmaxf(a10.w * lsc[c+3] + lsh[c+3], 0.f));
        u1[4] = f2bf(fmaxf(a11.x * lsc[c+4] + lsh[c+4], 0.f));
        u1[5] = f2bf(fmaxf(a11.y * lsc[c+5] + lsh[c+5], 0.f));
        u1[6] = f2bf(fmaxf(a11.z * lsc[c+6] + lsh[c+6], 0.f));
        u1[7] = f2bf(fmaxf(a11.w * lsc[c+7] + lsh[c+7], 0.f));
        *(uint4*)&As[t * 8]        = *(uint4*)u0;
        *(uint4*)&As[2048 + t * 8] = *(uint4*)u1;
        *(uint4*)&Bs[t * 8]        = b0;
        __syncthreads();
        const bf16x8 af0 = *(const bf16x8*)&As[aOff0];
        const bf16x8 af1 = *(const bf16x8*)&As[aOff1];
#pragma unroll
        for (int nt = 0; nt < 4; ++nt) {
            const bf16x8 bf = *(const bf16x8*)&Bs[bOff + nt * 512];
            acc[0][nt] = __builtin_amdgcn_mfma_f32_16x16x32_bf16(af0, bf, acc[0][nt], 0, 0, 0);
            acc[1][nt] = __builtin_amdgcn_mfma_f32_16x16x32_bf16(af1, bf, acc[1][nt], 0, 0, 0);
        }
    }
    const int rowBase = m0 + wave * 32;
#pragma unroll
    for (int mt = 0; mt < 2; ++mt) {
#pragma unroll
        for (int nt = 0; nt < 4; ++nt) {
            const int col = n0 + nt * 16 + l16;
#pragma unroll
            for (int r = 0; r < 4; ++r) {
                const int row = rowBase + mt * 16 + quad * 4 + r;
                C[(size_t)row * Nc + col] = f2bf(acc[mt][nt][r]);
            }
        }
    }
}

// ---------- per-node attention scores s,d : [N,H], from h (bf16) ----------
template <int H>
__global__ __launch_bounds__(128) void scores_kernel(
    const ushort* __restrict__ h, const float* __restrict__ a_src,
    const float* __restrict__ a_dst, float* __restrict__ s,
    float* __restrict__ d) {
    const int n = blockIdx.x, t = threadIdx.x;
    if (t < 32 * H) {
        const int head = t >> 5;
        const int c0 = (t & 31) * 4;
        const ushort4 hv = *(const ushort4*)&h[(size_t)n * (H * 128) + head * 128 + c0];
        const float4 as = *(const float4*)&a_src[head * 128 + c0];
        const float4 ad = *(const float4*)&a_dst[head * 128 + c0];
        const float h0 = bf2f(hv.x), h1 = bf2f(hv.y), h2 = bf2f(hv.z), h3 = bf2f(hv.w);
        float ps = h0 * as.x + h1 * as.y + h2 * as.z + h3 * as.w;
        float pd = h0 * ad.x + h1 * ad.y + h2 * ad.z + h3 * ad.w;
#pragma unroll
        for (int m = 16; m >= 1; m >>= 1) {
            ps += __shfl_xor(ps, m, 32);
            pd += __shfl_xor(pd, m, 32);
        }
        if ((t & 31) == 0) {
            s[n * H + head] = ps;
            d[n * H + head] = pd;
        }
    }
}

// ---------- CSR build ----------
__global__ void edge_hist(const int* __restrict__ ei, int E, int* __restrict__ cnt) {
    const int k = blockIdx.x * blockDim.x + threadIdx.x;
    const int ET = E + N_NODES;
    if (k < ET) {
        const int dstn = (k < E) ? ei[E + k] : (k - E);
        atomicAdd(&cnt[dstn], 1);
    }
}

__global__ __launch_bounds__(256) void scan_phase1(
    const int* __restrict__ cnt, int* __restrict__ incl,
    int* __restrict__ bsum, int n) {
    __shared__ int sh[256];
    const int b = blockIdx.x, t = threadIdx.x;
    const int i0 = b * 1024 + t * 4;
    int v[4]; int sum = 0;
#pragma unroll
    for (int k = 0; k < 4; ++k) {
        v[k] = (i0 + k < n) ? cnt[i0 + k] : 0;
        sum += v[k];
    }
    sh[t] = sum;
    __syncthreads();
    for (int off = 1; off < 256; off <<= 1) {
        const int a = (t >= off) ? sh[t - off] : 0;
        __syncthreads();
        sh[t] += a;
        __syncthreads();
    }
    int run = sh[t] - sum;
#pragma unroll
    for (int k = 0; k < 4; ++k) {
        run += v[k];
        if (i0 + k < n) incl[i0 + k] = run;
    }
    if (t == 255) bsum[b] = sh[255];
}

// fold of old phase2+3: each block inline-prefixes bsum (<=49 adds)
__global__ void scan_phase3b(const int* __restrict__ incl, const int* __restrict__ bsum,
                             int* __restrict__ rowptr, int* __restrict__ cursor, int n) {
    __shared__ int P[2];
    const int b = blockIdx.x;
    const int gA = (b * 256) >> 10;
    if (threadIdx.x == 0) {
        int p = 0;
        for (int k = 0; k < gA; ++k) p += bsum[k];
        P[0] = p;
        P[1] = (gA > 0) ? (p - bsum[gA - 1]) : 0;
    }
    __syncthreads();
    const int i = b * 256 + threadIdx.x;
    if (i < n) {
        rowptr[i + 1] = incl[i] + P[0];
        if (i == 0) cursor[0] = 0;
        else cursor[i] = incl[i - 1] + ((((i - 1) >> 10) == gA) ? P[0] : P[1]);
    }
    if (i == 0) rowptr[0] = 0;
}

__global__ void edge_scatter(const int* __restrict__ ei, int E,
                             int* __restrict__ cursor, int* __restrict__ col) {
    const int k = blockIdx.x * blockDim.x + threadIdx.x;
    const int ET = E + N_NODES;
    if (k < ET) {
        const int srcn = (k < E) ? ei[k] : (k - E);
        const int dstn = (k < E) ? ei[E + k] : (k - E);
        const int p = atomicAdd(&cursor[dstn], 1);
        col[p] = srcn;
    }
}

// ---------- aggregation H=4: 4 waves/block, one node per wave ----------
__global__ __launch_bounds__(256, 8) void aggregate4(
    const ushort* __restrict__ h, const float* __restrict__ s,
    const float* __restrict__ d, const int* __restrict__ rowptr,
    const int* __restrict__ col, const float* __restrict__ bias,
    float* __restrict__ y) {
    __shared__ int   ls[4][128];
    __shared__ float lex[4][512];
    const int t = threadIdx.x, w = t >> 6, lane = t & 63;
    const int n = blockIdx.x * 4 + w;
    const int head = lane >> 4;
    const int rs = rowptr[n], re = rowptr[n + 1], deg = re - rs;
    const float4 dn = *(const float4*)&d[n * 4];
    int* lsw = ls[w];
    float* lexw = lex[w];

    float acc[8];
#pragma unroll
    for (int k = 0; k < 8; ++k) acc[k] = 0.f;
    float4 dsum = make_float4(0.f, 0.f, 0.f, 0.f);
    float4 mx = make_float4(-3.4e38f, -3.4e38f, -3.4e38f, -3.4e38f);

    if (deg <= 128) {
#pragma unroll
        for (int it = 0; it < 2; ++it) {
            const int jj = lane + it * 64;
            if (jj < deg) {
                const int sn = col[rs + jj];
                lsw[jj] = sn;
                const float4 sv = *(const float4*)&s[sn * 4];
                float4 e;
                e.x = leaky(sv.x + dn.x); e.y = leaky(sv.y + dn.y);
                e.z = leaky(sv.z + dn.z); e.w = leaky(sv.w + dn.w);
                *(float4*)&lexw[jj * 4] = e;
                mx.x = fmaxf(mx.x, e.x); mx.y = fmaxf(mx.y, e.y);
                mx.z = fmaxf(mx.z, e.z); mx.w = fmaxf(mx.w, e.w);
            }
        }
#pragma unroll
        for (int off = 1; off < 64; off <<= 1) {
            mx.x = fmaxf(mx.x, __shfl_xor(mx.x, off));
            mx.y = fmaxf(mx.y, __shfl_xor(mx.y, off));
            mx.z = fmaxf(mx.z, __shfl_xor(mx.z, off));
            mx.w = fmaxf(mx.w, __shfl_xor(mx.w, off));
        }
#pragma unroll
        for (int it = 0; it < 2; ++it) {
            const int jj = lane + it * 64;
            if (jj < deg) {
                float4 e = *(const float4*)&lexw[jj * 4];
                e.x = __expf(e.x - mx.x); e.y = __expf(e.y - mx.y);
                e.z = __expf(e.z - mx.z); e.w = __expf(e.w - mx.w);
                *(float4*)&lexw[jj * 4] = e;
                dsum.x += e.x; dsum.y += e.y; dsum.z += e.z; dsum.w += e.w;
            }
        }
        wave_fence();
        int jj = 0;
        for (; jj + 2 <= deg; jj += 2) {
            const int sn0 = lsw[jj], sn1 = lsw[jj + 1];
            const float e0 = lexw[jj * 4 + head];
            const float e1 = lexw[(jj + 1) * 4 + head];
            const bf16x8 hv0 = *(const bf16x8*)&h[(size_t)sn0 * 512 + lane * 8];
            const bf16x8 hv1 = *(const bf16x8*)&h[(size_t)sn1 * 512 + lane * 8];
#pragma unroll
            for (int k = 0; k < 8; ++k) {
                acc[k] = fmaf(e0, bf2f((ushort)hv0[k]), acc[k]);
                acc[k] = fmaf(e1, bf2f((ushort)hv1[k]), acc[k]);
            }
        }
        if (jj < deg) {
            const int sn = lsw[jj];
            const float e0 = lexw[jj * 4 + head];
            const bf16x8 hv = *(const bf16x8*)&h[(size_t)sn * 512 + lane * 8];
#pragma unroll
            for (int k = 0; k < 8; ++k) acc[k] = fmaf(e0, bf2f((ushort)hv[k]), acc[k]);
        }
    } else {
        for (int j = rs + lane; j < re; j += 64) {
            const float4 sv = *(const float4*)&s[col[j] * 4];
            mx.x = fmaxf(mx.x, leaky(sv.x + dn.x));
            mx.y = fmaxf(mx.y, leaky(sv.y + dn.y));
            mx.z = fmaxf(mx.z, leaky(sv.z + dn.z));
            mx.w = fmaxf(mx.w, leaky(sv.w + dn.w));
        }
#pragma unroll
        for (int off = 1; off < 64; off <<= 1) {
            mx.x = fmaxf(mx.x, __shfl_xor(mx.x, off));
            mx.y = fmaxf(mx.y, __shfl_xor(mx.y, off));
            mx.z = fmaxf(mx.z, __shfl_xor(mx.z, off));
            mx.w = fmaxf(mx.w, __shfl_xor(mx.w, off));
        }
        for (int c0 = rs; c0 < re; c0 += 128) {
            const int cend = min(re, c0 + 128);
#pragma unroll
            for (int it = 0; it < 2; ++it) {
                const int j = c0 + lane + it * 64;
                if (j < cend) {
                    const int sn = col[j];
                    const int jj = j - c0;
                    lsw[jj] = sn;
                    const float4 sv = *(const float4*)&s[sn * 4];
                    float4 e;
                    e.x = __expf(leaky(sv.x + dn.x) - mx.x);
                    e.y = __expf(leaky(sv.y + dn.y) - mx.y);
                    e.z = __expf(leaky(sv.z + dn.z) - mx.z);
                    e.w = __expf(leaky(sv.w + dn.w) - mx.w);
                    *(float4*)&lexw[jj * 4] = e;
                    dsum.x += e.x; dsum.y += e.y; dsum.z += e.z; dsum.w += e.w;
                }
            }
            wave_fence();
            const int cnum = cend - c0;
            for (int jj = 0; jj < cnum; ++jj) {
                const int sn = lsw[jj];
                const float exh = lexw[jj * 4 + head];
                const bf16x8 hv = *(const bf16x8*)&h[(size_t)sn * 512 + lane * 8];
#pragma unroll
                for (int k = 0; k < 8; ++k) acc[k] = fmaf(exh, bf2f((ushort)hv[k]), acc[k]);
            }
            wave_fence();
        }
    }

#pragma unroll
    for (int off = 1; off < 64; off <<= 1) {
        dsum.x += __shfl_xor(dsum.x, off);
        dsum.y += __shfl_xor(dsum.y, off);
        dsum.z += __shfl_xor(dsum.z, off);
        dsum.w += __shfl_xor(dsum.w, off);
    }
    const float dsel = (head == 0) ? dsum.x : (head == 1) ? dsum.y
                     : (head == 2) ? dsum.z : dsum.w;
    const float inv = 1.f / (dsel + 1e-16f);
    wave_fence();
#pragma unroll
    for (int k = 0; k < 8; ++k) lexw[lane * 8 + k] = acc[k] * inv;
    wave_fence();
    {
        const int c = lane * 2;
        const float m0 = 0.25f * (lexw[c] + lexw[128 + c] + lexw[256 + c] + lexw[384 + c]);
        const float m1 = 0.25f * (lexw[c + 1] + lexw[128 + c + 1] + lexw[256 + c + 1] + lexw[384 + c + 1]);
        float2 o = make_float2(m0 + bias[c], m1 + bias[c + 1]);
        *(float2*)&y[(size_t)n * 128 + c] = o;
    }
}

// ---------- aggregation H=1 ----------
__global__ __launch_bounds__(256, 8) void aggregate1(
    const ushort* __restrict__ h, const float* __restrict__ s,
    const float* __restrict__ d, const int* __restrict__ rowptr,
    const int* __restrict__ col, const float* __restrict__ bias,
    float* __restrict__ y) {
    __shared__ int   ls[4][128];
    __shared__ float lex[4][128];
    const int t = threadIdx.x, w = t >> 6, lane = t & 63;
    const int n = blockIdx.x * 4 + w;
    const int rs = rowptr[n], re = rowptr[n + 1], deg = re - rs;
    const float dn = d[n];
    int* lsw = ls[w];
    float* lexw = lex[w];

    float acc0 = 0.f, acc1 = 0.f, dsum = 0.f;
    float mx = -3.4e38f;

    if (deg <= 128) {
#pragma unroll
        for (int it = 0; it < 2; ++it) {
            const int jj = lane + it * 64;
            if (jj < deg) {
                const int sn = col[rs + jj];
                lsw[jj] = sn;
                const float e = leaky(s[sn] + dn);
                lexw[jj] = e;
                mx = fmaxf(mx, e);
            }
        }
#pragma unroll
        for (int off = 1; off < 64; off <<= 1) mx = fmaxf(mx, __shfl_xor(mx, off));
#pragma unroll
        for (int it = 0; it < 2; ++it) {
            const int jj = lane + it * 64;
            if (jj < deg) {
                const float ex = __expf(lexw[jj] - mx);
                lexw[jj] = ex;
                dsum += ex;
            }
        }
        wave_fence();
        int jj = 0;
        for (; jj + 2 <= deg; jj += 2) {
            const int sn0 = lsw[jj], sn1 = lsw[jj + 1];
            const float e0 = lexw[jj], e1 = lexw[jj + 1];
            const ushort2 hv0 = *(const ushort2*)&h[(size_t)sn0 * 128 + lane * 2];
            const ushort2 hv1 = *(const ushort2*)&h[(size_t)sn1 * 128 + lane * 2];
            acc0 = fmaf(e0, bf2f(hv0.x), acc0); acc1 = fmaf(e0, bf2f(hv0.y), acc1);
            acc0 = fmaf(e1, bf2f(hv1.x), acc0); acc1 = fmaf(e1, bf2f(hv1.y), acc1);
        }
        if (jj < deg) {
            const int sn = lsw[jj];
            const float ex = lexw[jj];
            const ushort2 hv = *(const ushort2*)&h[(size_t)sn * 128 + lane * 2];
            acc0 = fmaf(ex, bf2f(hv.x), acc0);
            acc1 = fmaf(ex, bf2f(hv.y), acc1);
        }
    } else {
        for (int j = rs + lane; j < re; j += 64) {
            mx = fmaxf(mx, leaky(s[col[j]] + dn));
        }
#pragma unroll
        for (int off = 1; off < 64; off <<= 1) mx = fmaxf(mx, __shfl_xor(mx, off));
        for (int c0 = rs; c0 < re; c0 += 128) {
            const int cend = min(re, c0 + 128);
#pragma unroll
            for (int it = 0; it < 2; ++it) {
                const int j = c0 + lane + it * 64;
                if (j < cend) {
                    const int sn = col[j];
                    const int jj = j - c0;
                    lsw[jj] = sn;
                    const float ex = __expf(leaky(s[sn] + dn) - mx);
                    lexw[jj] = ex;
                    dsum += ex;
                }
            }
            wave_fence();
            const int cnum = cend - c0;
            for (int jj = 0; jj < cnum; ++jj) {
                const int sn = lsw[jj];
                const float ex = lexw[jj];
                const ushort2 hv = *(const ushort2*)&h[(size_t)sn * 128 + lane * 2];
                acc0 = fmaf(ex, bf2f(hv.x), acc0);
                acc1 = fmaf(ex, bf2f(hv.y), acc1);
            }
            wave_fence();
        }
    }
#pragma unroll
    for (int off = 1; off < 64; off <<= 1) dsum += __shfl_xor(dsum, off);
    const float inv = 1.f / (dsum + 1e-16f);
    const int c = lane * 2;
    float2 o = make_float2(acc0 * inv + bias[c], acc1 * inv + bias[c + 1]);
    *(float2*)&y[(size_t)n * 128 + c] = o;
}

// ---------- fused BatchNorm stats: partial sums + last-block reduce ----------
__global__ __launch_bounds__(256) void bn_stats_fused(
    const float* __restrict__ y, float* __restrict__ partial,
    const float* __restrict__ gamma, const float* __restrict__ beta,
    float* __restrict__ stats, unsigned* __restrict__ ticket) {
    const int b = blockIdx.x, t = threadIdx.x;
    const int c = t & 127;
    float sum = 0.f, sq = 0.f;
    for (int r = b * 2 + (t >> 7); r < N_NODES; r += 512) {
        const float v = y[(size_t)r * 128 + c];
        sum += v;
        sq += v * v;
    }
    __shared__ float s1[256], s2[256];
    s1[t] = sum; s2[t] = sq;
    __syncthreads();
    if (t < 128) {
        partial[(size_t)b * 256 + c] = s1[t] + s1[t + 128];
        partial[(size_t)b * 256 + 128 + c] = s2[t] + s2[t + 128];
    }
    __threadfence();
    __shared__ unsigned rank;
    if (t == 0) rank = atomicAdd(ticket, 1u);
    __syncthreads();
    if (rank == 255u) {
        __threadfence();
        if (t < 128) {
            float S = 0.f, Q = 0.f;
            for (int b2 = 0; b2 < 256; ++b2) {
                S += partial[(size_t)b2 * 256 + t];
                Q += partial[(size_t)b2 * 256 + 128 + t];
            }
            const float mu = S / (float)N_NODES;
            const float var = Q / (float)N_NODES - mu * mu;
            const float sc = gamma[t] * rsqrtf(var + EPS_BN);
            stats[t] = sc;
            stats[128 + t] = beta[t] - mu * sc;
        }
    }
}

// final BN -> fp32 d_out (no relu)
__global__ void bn_apply_out(const float* __restrict__ y,
                             const float* __restrict__ stats,
                             float* __restrict__ out) {
    const int i = blockIdx.x * blockDim.x + threadIdx.x;
    if (i < N_NODES * 128) {
        const int c = i & 127;
        out[i] = y[i] * stats[c] + stats[128 + c];
    }
}

// ---------- launch ----------
extern "C" void kernel_launch(void* const* d_in, const int* in_sizes, int n_in,
                              void* d_out, int out_size, void* d_ws, size_t ws_size,
                              hipStream_t stream) {
    const float* x = (const float*)d_in[0];
    const int* ei = (const int*)d_in[1];
    const int E = in_sizes[1] / 2;
    const int ET = E + N_NODES;

    const float* W[3]    = {(const float*)d_in[2], (const float*)d_in[8],  (const float*)d_in[14]};
    const float* ASRC[3] = {(const float*)d_in[3], (const float*)d_in[9],  (const float*)d_in[15]};
    const float* ADST[3] = {(const float*)d_in[4], (const float*)d_in[10], (const float*)d_in[16]};
    const float* BIAS[3] = {(const float*)d_in[5], (const float*)d_in[11], (const float*)d_in[17]};
    const float* GAM[3]  = {(const float*)d_in[6], (const float*)d_in[12], (const float*)d_in[18]};
    const float* BET[3]  = {(const float*)d_in[7], (const float*)d_in[13], (const float*)d_in[19]};

    char* base = (char*)d_ws;
    auto alloc = [&](size_t bytes) {
        char* p = base;
        base += (bytes + 255) & ~(size_t)255;
        return p;
    };
    ushort* hbf    = (ushort*)alloc((size_t)M_PAD * 512 * 2);
    ushort* Xbf    = (ushort*)alloc((size_t)M_PAD * 256 * 2);
    ushort* Wt0    = (ushort*)alloc((size_t)512 * 256 * 2);
    ushort* Wt1    = (ushort*)alloc((size_t)512 * 128 * 2);
    ushort* Wt2    = (ushort*)alloc((size_t)128 * 128 * 2);
    float*  y      = (float*)alloc((size_t)M_PAD * 128 * 4);
    float*  s      = (float*)alloc((size_t)N_NODES * 4 * 4);
    float*  dsc    = (float*)alloc((size_t)N_NODES * 4 * 4);
    int*    rowptr = (int*)alloc((size_t)(N_NODES + 1) * 4);
    int*    col    = (int*)alloc((size_t)ET * 4);
    int*    cnt    = (int*)alloc((size_t)(N_NODES + 8) * 4);   // +8: bn tickets
    int*    incl   = (int*)alloc((size_t)N_NODES * 4);
    int*    bsum   = (int*)alloc((size_t)64 * 4);
    float*  partial = (float*)alloc((size_t)256 * 256 * 4);
    float*  stats   = (float*)alloc((size_t)256 * 4);
    if ((size_t)(base - (char*)d_ws) > ws_size) return;

    unsigned* tickets = (unsigned*)(cnt + N_NODES);

    const int eb = (ET + 255) / 256;
    const int nScanB = (N_NODES + 1023) / 1024;

    // --- CSR build + ticket zeroing (one memset covers cnt and tickets) ---
    hipMemsetAsync(cnt, 0, (size_t)(N_NODES + 8) * 4, stream);
    edge_hist<<<eb, 256, 0, stream>>>(ei, E, cnt);
    scan_phase1<<<nScanB, 256, 0, stream>>>(cnt, incl, bsum, N_NODES);
    scan_phase3b<<<(N_NODES + 255) / 256, 256, 0, stream>>>(incl, bsum, rowptr, cnt, N_NODES);
    edge_scatter<<<eb, 256, 0, stream>>>(ei, E, cnt, col);

    // --- prep: x -> bf16 padded, all weight transposes ---
    prep<<<(M_PAD * 256 / 4 + 255) / 256, 256, 0, stream>>>(
        x, Xbf, W[0], W[1], W[2], Wt0, Wt1, Wt2);

    // ---- layer 0 (H=4, K=256) ----
    {
        dim3 g0(512 / 64, M_PAD / 128);
        gemm_bf<<<g0, 256, 0, stream>>>(Xbf, Wt0, hbf, 256, 512);
        scores_kernel<4><<<N_NODES, 128, 0, stream>>>(hbf, ASRC[0], ADST[0], s, dsc);
        aggregate4<<<N_NODES / 4, 256, 0, stream>>>(hbf, s, dsc, rowptr, col, BIAS[0], y);
        bn_stats_fused<<<256, 256, 0, stream>>>(y, partial, GAM[0], BET[0], stats, tickets + 0);
    }
    // ---- layer 1 (H=4, K=128, BN+ReLU fused into gemm prologue) ----
    {
        dim3 g1(512 / 64, M_PAD / 128);
        gemm_bn<<<g1, 256, 0, stream>>>(y, stats, Wt1, hbf, 512);
        scores_kernel<4><<<N_NODES, 128, 0, stream>>>(hbf, ASRC[1], ADST[1], s, dsc);
        aggregate4<<<N_NODES / 4, 256, 0, stream>>>(hbf, s, dsc, rowptr, col, BIAS[1], y);
        bn_stats_fused<<<256, 256, 0, stream>>>(y, partial, GAM[1], BET[1], stats, tickets + 1);
    }
    // ---- layer 2 (H=1, K=128) ----
    {
        dim3 g2(128 / 64, M_PAD / 128);
        gemm_bn<<<g2, 256, 0, stream>>>(y, stats, Wt2, hbf, 128);
        scores_kernel<1><<<N_NODES, 128, 0, stream>>>(hbf, ASRC[2], ADST[2], s, dsc);
        aggregate1<<<N_NODES / 4, 256, 0, stream>>>(hbf, s, dsc, rowptr, col, BIAS[2], y);
        bn_stats_fused<<<256, 256, 0, stream>>>(y, partial, GAM[2], BET[2], stats, tickets + 2);
    }
    bn_apply_out<<<(N_NODES * 128 + 255) / 256, 256, 0, stream>>>(y, stats, (float*)d_out);
}

// Round 7
// 571.072 us; speedup vs baseline: 1.4160x; 1.1213x over previous
//
#include <hip/hip_runtime.h>
#include <cstdint>
#include <cstddef>

#define N_NODES 50000
#define M_PAD   50176   // 392 * 128
#define EPS_BN  1e-5f
#define NEG     0.2f

typedef __attribute__((ext_vector_type(8))) short bf16x8;
typedef __attribute__((ext_vector_type(4))) float f32x4;

// ---------- bf16 helpers ----------
static __device__ __forceinline__ ushort f2bf(float f) {
    unsigned u = __float_as_uint(f);
    unsigned r = (u + 0x7FFFu + ((u >> 16) & 1u)) >> 16;   // RNE
    return (ushort)r;
}
static __device__ __forceinline__ float bf2f(ushort b) {
    return __uint_as_float(((unsigned)b) << 16);
}
static __device__ __forceinline__ float leaky(float v) {
    return (v > 0.f) ? v : NEG * v;
}
static __device__ __forceinline__ void wave_fence() {
    __builtin_amdgcn_fence(__ATOMIC_ACQ_REL, "wavefront");
}

// ---------- prep: conv_x + all 3 weight transposes + edge histogram ----------
__global__ __launch_bounds__(256) void prep(
    const float* __restrict__ x, ushort* __restrict__ Xbf,
    const float* __restrict__ W0, const float* __restrict__ W1,
    const float* __restrict__ W2, ushort* __restrict__ Wt0,
    ushort* __restrict__ Wt1, ushort* __restrict__ Wt2,
    const int* __restrict__ ei, int E, int* __restrict__ cnt) {
    const int gi = blockIdx.x * 256 + threadIdx.x;
    // part 1: x conversion, 4 elems/thread
    const int e0 = gi * 4;
    if (e0 < M_PAD * 256) {
        const int row = e0 >> 8;
        ushort4 o;
        if (row < N_NODES) {
            const float4 v = *(const float4*)&x[e0];
            o = make_ushort4(f2bf(v.x), f2bf(v.y), f2bf(v.z), f2bf(v.w));
        } else {
            o = make_ushort4(0, 0, 0, 0);
        }
        *(ushort4*)&Xbf[e0] = o;
    }
    // part 2: weight transposes
    if (gi < 131072) {                       // W0: 256x512
        const int k = gi >> 9, n = gi & 511;
        Wt0[(size_t)n * 256 + k] = f2bf(W0[gi]);
    } else if (gi < 196608) {                // W1: 128x512
        const int j = gi - 131072;
        const int k = j >> 9, n = j & 511;
        Wt1[(size_t)n * 128 + k] = f2bf(W1[j]);
    } else if (gi < 212992) {                // W2: 128x128
        const int j = gi - 196608;
        const int k = j >> 7, n = j & 127;
        Wt2[(size_t)n * 128 + k] = f2bf(W2[j]);
    }
    // part 3: edge histogram (dst degrees incl. self-loops)
    const int ET = E + N_NODES;
    if (gi < ET) {
        const int dstn = (gi < E) ? ei[E + gi] : (gi - E);
        atomicAdd(&cnt[dstn], 1);
    }
}

// ---------- fused MFMA GEMM (BM=128,BN=128,BK=32) + per-row attention scores ----------
// BNIN=false: A = Abf (bf16 [M_PAD,K]); BNIN=true: A = bn_relu(Y fp32 [M_PAD,128]) via stats.
// Each block covers a FULL head (128 cols): epilogue computes
// s[row,hd] = sum_c C[row,c]*a_src[hd,c], d likewise, from fp32 accumulators.
template <bool BNIN>
__global__ __launch_bounds__(256, 4) void gemm_fused(
    const ushort* __restrict__ Abf, const float* __restrict__ Y,
    const float* __restrict__ stats, const ushort* __restrict__ Bt,
    ushort* __restrict__ C, int K, int Nc, int H,
    const float* __restrict__ a_src, const float* __restrict__ a_dst,
    float* __restrict__ s, float* __restrict__ d) {
    __shared__ ushort As[128 * 32];
    __shared__ ushort Bs[128 * 32];
    __shared__ float lsc[128], lsh[128];
    const int t = threadIdx.x;
    if (BNIN && t < 128) { lsc[t] = stats[t]; lsh[t] = stats[128 + t]; }
    const int wave = t >> 6, lane = t & 63;
    const int quad = lane >> 4, l16 = lane & 15;
    const int m0 = blockIdx.y * 128, n0 = blockIdx.x * 128;
    const int hd = n0 >> 7;

    const int aRow = t >> 2, aCol = (t & 3) * 8;
    const ushort* aG0 = Abf + (size_t)(m0 + aRow) * K + aCol;
    const ushort* aG1 = Abf + (size_t)(m0 + 64 + aRow) * K + aCol;
    const float*  yG0 = Y + (size_t)(m0 + aRow) * 128 + aCol;
    const float*  yG1 = Y + (size_t)(m0 + 64 + aRow) * 128 + aCol;
    const ushort* bG0 = Bt + (size_t)(n0 + aRow) * K + aCol;
    const ushort* bG1 = Bt + (size_t)(n0 + 64 + aRow) * K + aCol;

    const int aOff0 = (wave * 32 + l16) * 32 + quad * 8;
    const int aOff1 = aOff0 + 16 * 32;

    f32x4 acc[2][8] = {};
    for (int k0 = 0; k0 < K; k0 += 32) {
        uint4 sa0, sa1;
        if constexpr (BNIN) {
            const float4 a00 = *(const float4*)(yG0 + k0);
            const float4 a01 = *(const float4*)(yG0 + k0 + 4);
            const float4 a10 = *(const float4*)(yG1 + k0);
            const float4 a11 = *(const float4*)(yG1 + k0 + 4);
            const int c = aCol + k0;
            __syncthreads();
            ushort u0[8], u1[8];
            u0[0] = f2bf(fmaxf(a00.x * lsc[c+0] + lsh[c+0], 0.f));
            u0[1] = f2bf(fmaxf(a00.y * lsc[c+1] + lsh[c+1], 0.f));
            u0[2] = f2bf(fmaxf(a00.z * lsc[c+2] + lsh[c+2], 0.f));
            u0[3] = f2bf(fmaxf(a00.w * lsc[c+3] + lsh[c+3], 0.f));
            u0[4] = f2bf(fmaxf(a01.x * lsc[c+4] + lsh[c+4], 0.f));
            u0[5] = f2bf(fmaxf(a01.y * lsc[c+5] + lsh[c+5], 0.f));
            u0[6] = f2bf(fmaxf(a01.z * lsc[c+6] + lsh[c+6], 0.f));
            u0[7] = f2bf(fmaxf(a01.w * lsc[c+7] + lsh[c+7], 0.f));
            u1[0] = f2bf(fmaxf(a10.x * lsc[c+0] + lsh[c+0], 0.f));
            u1[1] = f2bf(fmaxf(a10.y * lsc[c+1] + lsh[c+1], 0.f));
            u1[2] = f2bf(fmaxf(a10.z * lsc[c+2] + lsh[c+2], 0.f));
            u1[3] = f2bf(fmaxf(a10.w * lsc[c+3] + lsh[c+3], 0.f));
            u1[4] = f2bf(fmaxf(a11.x * lsc[c+4] + lsh[c+4], 0.f));
            u1[5] = f2bf(fmaxf(a11.y * lsc[c+5] + lsh[c+5], 0.f));
            u1[6] = f2bf(fmaxf(a11.z * lsc[c+6] + lsh[c+6], 0.f));
            u1[7] = f2bf(fmaxf(a11.w * lsc[c+7] + lsh[c+7], 0.f));
            sa0 = *(uint4*)u0;
            sa1 = *(uint4*)u1;
            const uint4 b0 = *(const uint4*)(bG0 + k0);
            const uint4 b1 = *(const uint4*)(bG1 + k0);
            *(uint4*)&As[t * 8]        = sa0;
            *(uint4*)&As[2048 + t * 8] = sa1;
            *(uint4*)&Bs[t * 8]        = b0;
            *(uint4*)&Bs[2048 + t * 8] = b1;
        } else {
            sa0 = *(const uint4*)(aG0 + k0);
            sa1 = *(const uint4*)(aG1 + k0);
            const uint4 b0 = *(const uint4*)(bG0 + k0);
            const uint4 b1 = *(const uint4*)(bG1 + k0);
            __syncthreads();
            *(uint4*)&As[t * 8]        = sa0;
            *(uint4*)&As[2048 + t * 8] = sa1;
            *(uint4*)&Bs[t * 8]        = b0;
            *(uint4*)&Bs[2048 + t * 8] = b1;
        }
        __syncthreads();
        const bf16x8 af0 = *(const bf16x8*)&As[aOff0];
        const bf16x8 af1 = *(const bf16x8*)&As[aOff1];
#pragma unroll
        for (int nt = 0; nt < 8; ++nt) {
            const bf16x8 bf = *(const bf16x8*)&Bs[(nt * 16 + l16) * 32 + quad * 8];
            acc[0][nt] = __builtin_amdgcn_mfma_f32_16x16x32_bf16(af0, bf, acc[0][nt], 0, 0, 0);
            acc[1][nt] = __builtin_amdgcn_mfma_f32_16x16x32_bf16(af1, bf, acc[1][nt], 0, 0, 0);
        }
    }

    // ---- C store (bf16) ----
    const int rowBase = m0 + wave * 32;
#pragma unroll
    for (int mt = 0; mt < 2; ++mt) {
#pragma unroll
        for (int nt = 0; nt < 8; ++nt) {
            const int col = n0 + nt * 16 + l16;
#pragma unroll
            for (int r = 0; r < 4; ++r) {
                const int row = rowBase + mt * 16 + quad * 4 + r;
                C[(size_t)row * Nc + col] = f2bf(acc[mt][nt][r]);
            }
        }
    }

    // ---- fused scores: s/d[row,hd] from fp32 accumulators ----
    float aS[8], aD[8];
#pragma unroll
    for (int nt = 0; nt < 8; ++nt) {
        aS[nt] = a_src[hd * 128 + nt * 16 + l16];
        aD[nt] = a_dst[hd * 128 + nt * 16 + l16];
    }
    float ps[2][4], pd[2][4];
#pragma unroll
    for (int mt = 0; mt < 2; ++mt)
#pragma unroll
        for (int r = 0; r < 4; ++r) {
            float vs = 0.f, vd = 0.f;
#pragma unroll
            for (int nt = 0; nt < 8; ++nt) {
                vs = fmaf(acc[mt][nt][r], aS[nt], vs);
                vd = fmaf(acc[mt][nt][r], aD[nt], vd);
            }
            ps[mt][r] = vs; pd[mt][r] = vd;
        }
#pragma unroll
    for (int off = 1; off < 16; off <<= 1) {
#pragma unroll
        for (int mt = 0; mt < 2; ++mt)
#pragma unroll
            for (int r = 0; r < 4; ++r) {
                ps[mt][r] += __shfl_xor(ps[mt][r], off);
                pd[mt][r] += __shfl_xor(pd[mt][r], off);
            }
    }
    if (l16 == 0) {
#pragma unroll
        for (int mt = 0; mt < 2; ++mt)
#pragma unroll
            for (int r = 0; r < 4; ++r) {
                const int row = rowBase + mt * 16 + quad * 4 + r;
                if (row < N_NODES) {
                    s[row * H + hd] = ps[mt][r];
                    d[row * H + hd] = pd[mt][r];
                }
            }
    }
}

// ---------- CSR scan ----------
__global__ __launch_bounds__(256) void scan_phase1(
    const int* __restrict__ cnt, int* __restrict__ incl,
    int* __restrict__ bsum, int n) {
    __shared__ int sh[256];
    const int b = blockIdx.x, t = threadIdx.x;
    const int i0 = b * 1024 + t * 4;
    int v[4]; int sum = 0;
#pragma unroll
    for (int k = 0; k < 4; ++k) {
        v[k] = (i0 + k < n) ? cnt[i0 + k] : 0;
        sum += v[k];
    }
    sh[t] = sum;
    __syncthreads();
    for (int off = 1; off < 256; off <<= 1) {
        const int a = (t >= off) ? sh[t - off] : 0;
        __syncthreads();
        sh[t] += a;
        __syncthreads();
    }
    int run = sh[t] - sum;
#pragma unroll
    for (int k = 0; k < 4; ++k) {
        run += v[k];
        if (i0 + k < n) incl[i0 + k] = run;
    }
    if (t == 255) bsum[b] = sh[255];
}

__global__ void scan_phase3b(const int* __restrict__ incl, const int* __restrict__ bsum,
                             int* __restrict__ rowptr, int* __restrict__ cursor, int n) {
    __shared__ int P[2];
    const int b = blockIdx.x;
    const int gA = (b * 256) >> 10;
    if (threadIdx.x == 0) {
        int p = 0;
        for (int k = 0; k < gA; ++k) p += bsum[k];
        P[0] = p;
        P[1] = (gA > 0) ? (p - bsum[gA - 1]) : 0;
    }
    __syncthreads();
    const int i = b * 256 + threadIdx.x;
    if (i < n) {
        rowptr[i + 1] = incl[i] + P[0];
        if (i == 0) cursor[0] = 0;
        else cursor[i] = incl[i - 1] + ((((i - 1) >> 10) == gA) ? P[0] : P[1]);
    }
    if (i == 0) rowptr[0] = 0;
}

__global__ void edge_scatter(const int* __restrict__ ei, int E,
                             int* __restrict__ cursor, int* __restrict__ col) {
    const int k = blockIdx.x * blockDim.x + threadIdx.x;
    const int ET = E + N_NODES;
    if (k < ET) {
        const int srcn = (k < E) ? ei[k] : (k - E);
        const int dstn = (k < E) ? ei[E + k] : (k - E);
        const int p = atomicAdd(&cursor[dstn], 1);
        col[p] = srcn;
    }
}

// ---------- aggregation H=4: 4 waves/block, one node per wave ----------
__global__ __launch_bounds__(256, 8) void aggregate4(
    const ushort* __restrict__ h, const float* __restrict__ s,
    const float* __restrict__ d, const int* __restrict__ rowptr,
    const int* __restrict__ col, const float* __restrict__ bias,
    float* __restrict__ y) {
    __shared__ int   ls[4][128];
    __shared__ float lex[4][512];
    const int t = threadIdx.x, w = t >> 6, lane = t & 63;
    const int n = blockIdx.x * 4 + w;
    const int head = lane >> 4;
    const int rs = rowptr[n], re = rowptr[n + 1], deg = re - rs;
    const float4 dn = *(const float4*)&d[n * 4];
    int* lsw = ls[w];
    float* lexw = lex[w];

    float acc[8];
#pragma unroll
    for (int k = 0; k < 8; ++k) acc[k] = 0.f;
    float4 dsum = make_float4(0.f, 0.f, 0.f, 0.f);
    float4 mx = make_float4(-3.4e38f, -3.4e38f, -3.4e38f, -3.4e38f);

    if (deg <= 128) {
#pragma unroll
        for (int it = 0; it < 2; ++it) {
            const int jj = lane + it * 64;
            if (jj < deg) {
                const int sn = col[rs + jj];
                lsw[jj] = sn;
                const float4 sv = *(const float4*)&s[sn * 4];
                float4 e;
                e.x = leaky(sv.x + dn.x); e.y = leaky(sv.y + dn.y);
                e.z = leaky(sv.z + dn.z); e.w = leaky(sv.w + dn.w);
                *(float4*)&lexw[jj * 4] = e;
                mx.x = fmaxf(mx.x, e.x); mx.y = fmaxf(mx.y, e.y);
                mx.z = fmaxf(mx.z, e.z); mx.w = fmaxf(mx.w, e.w);
            }
        }
#pragma unroll
        for (int off = 1; off < 64; off <<= 1) {
            mx.x = fmaxf(mx.x, __shfl_xor(mx.x, off));
            mx.y = fmaxf(mx.y, __shfl_xor(mx.y, off));
            mx.z = fmaxf(mx.z, __shfl_xor(mx.z, off));
            mx.w = fmaxf(mx.w, __shfl_xor(mx.w, off));
        }
#pragma unroll
        for (int it = 0; it < 2; ++it) {
            const int jj = lane + it * 64;
            if (jj < deg) {
                float4 e = *(const float4*)&lexw[jj * 4];
                e.x = __expf(e.x - mx.x); e.y = __expf(e.y - mx.y);
                e.z = __expf(e.z - mx.z); e.w = __expf(e.w - mx.w);
                *(float4*)&lexw[jj * 4] = e;
                dsum.x += e.x; dsum.y += e.y; dsum.z += e.z; dsum.w += e.w;
            }
        }
        wave_fence();
        int jj = 0;
        for (; jj + 4 <= deg; jj += 4) {
            const int sn0 = lsw[jj], sn1 = lsw[jj + 1];
            const int sn2 = lsw[jj + 2], sn3 = lsw[jj + 3];
            const float e0 = lexw[jj * 4 + head];
            const float e1 = lexw[(jj + 1) * 4 + head];
            const float e2 = lexw[(jj + 2) * 4 + head];
            const float e3 = lexw[(jj + 3) * 4 + head];
            const bf16x8 hv0 = *(const bf16x8*)&h[(size_t)sn0 * 512 + lane * 8];
            const bf16x8 hv1 = *(const bf16x8*)&h[(size_t)sn1 * 512 + lane * 8];
            const bf16x8 hv2 = *(const bf16x8*)&h[(size_t)sn2 * 512 + lane * 8];
            const bf16x8 hv3 = *(const bf16x8*)&h[(size_t)sn3 * 512 + lane * 8];
#pragma unroll
            for (int k = 0; k < 8; ++k) {
                acc[k] = fmaf(e0, bf2f((ushort)hv0[k]), acc[k]);
                acc[k] = fmaf(e1, bf2f((ushort)hv1[k]), acc[k]);
                acc[k] = fmaf(e2, bf2f((ushort)hv2[k]), acc[k]);
                acc[k] = fmaf(e3, bf2f((ushort)hv3[k]), acc[k]);
            }
        }
        for (; jj < deg; ++jj) {
            const int sn = lsw[jj];
            const float e0 = lexw[jj * 4 + head];
            const bf16x8 hv = *(const bf16x8*)&h[(size_t)sn * 512 + lane * 8];
#pragma unroll
            for (int k = 0; k < 8; ++k) acc[k] = fmaf(e0, bf2f((ushort)hv[k]), acc[k]);
        }
    } else {
        for (int j = rs + lane; j < re; j += 64) {
            const float4 sv = *(const float4*)&s[col[j] * 4];
            mx.x = fmaxf(mx.x, leaky(sv.x + dn.x));
            mx.y = fmaxf(mx.y, leaky(sv.y + dn.y));
            mx.z = fmaxf(mx.z, leaky(sv.z + dn.z));
            mx.w = fmaxf(mx.w, leaky(sv.w + dn.w));
        }
#pragma unroll
        for (int off = 1; off < 64; off <<= 1) {
            mx.x = fmaxf(mx.x, __shfl_xor(mx.x, off));
            mx.y = fmaxf(mx.y, __shfl_xor(mx.y, off));
            mx.z = fmaxf(mx.z, __shfl_xor(mx.z, off));
            mx.w = fmaxf(mx.w, __shfl_xor(mx.w, off));
        }
        for (int c0 = rs; c0 < re; c0 += 128) {
            const int cend = min(re, c0 + 128);
#pragma unroll
            for (int it = 0; it < 2; ++it) {
                const int j = c0 + lane + it * 64;
                if (j < cend) {
                    const int sn = col[j];
                    const int jj = j - c0;
                    lsw[jj] = sn;
                    const float4 sv = *(const float4*)&s[sn * 4];
                    float4 e;
                    e.x = __expf(leaky(sv.x + dn.x) - mx.x);
                    e.y = __expf(leaky(sv.y + dn.y) - mx.y);
                    e.z = __expf(leaky(sv.z + dn.z) - mx.z);
                    e.w = __expf(leaky(sv.w + dn.w) - mx.w);
                    *(float4*)&lexw[jj * 4] = e;
                    dsum.x += e.x; dsum.y += e.y; dsum.z += e.z; dsum.w += e.w;
                }
            }
            wave_fence();
            const int cnum = cend - c0;
            for (int jj = 0; jj < cnum; ++jj) {
                const int sn = lsw[jj];
                const float exh = lexw[jj * 4 + head];
                const bf16x8 hv = *(const bf16x8*)&h[(size_t)sn * 512 + lane * 8];
#pragma unroll
                for (int k = 0; k < 8; ++k) acc[k] = fmaf(exh, bf2f((ushort)hv[k]), acc[k]);
            }
            wave_fence();
        }
    }

#pragma unroll
    for (int off = 1; off < 64; off <<= 1) {
        dsum.x += __shfl_xor(dsum.x, off);
        dsum.y += __shfl_xor(dsum.y, off);
        dsum.z += __shfl_xor(dsum.z, off);
        dsum.w += __shfl_xor(dsum.w, off);
    }
    const float dsel = (head == 0) ? dsum.x : (head == 1) ? dsum.y
                     : (head == 2) ? dsum.z : dsum.w;
    const float inv = 1.f / (dsel + 1e-16f);
    wave_fence();
#pragma unroll
    for (int k = 0; k < 8; ++k) lexw[lane * 8 + k] = acc[k] * inv;
    wave_fence();
    {
        const int c = lane * 2;
        const float m0 = 0.25f * (lexw[c] + lexw[128 + c] + lexw[256 + c] + lexw[384 + c]);
        const float m1 = 0.25f * (lexw[c + 1] + lexw[128 + c + 1] + lexw[256 + c + 1] + lexw[384 + c + 1]);
        float2 o = make_float2(m0 + bias[c], m1 + bias[c + 1]);
        *(float2*)&y[(size_t)n * 128 + c] = o;
    }
}

// ---------- aggregation H=1 ----------
__global__ __launch_bounds__(256, 8) void aggregate1(
    const ushort* __restrict__ h, const float* __restrict__ s,
    const float* __restrict__ d, const int* __restrict__ rowptr,
    const int* __restrict__ col, const float* __restrict__ bias,
    float* __restrict__ y) {
    __shared__ int   ls[4][128];
    __shared__ float lex[4][128];
    const int t = threadIdx.x, w = t >> 6, lane = t & 63;
    const int n = blockIdx.x * 4 + w;
    const int rs = rowptr[n], re = rowptr[n + 1], deg = re - rs;
    const float dn = d[n];
    int* lsw = ls[w];
    float* lexw = lex[w];

    float acc0 = 0.f, acc1 = 0.f, dsum = 0.f;
    float mx = -3.4e38f;

    if (deg <= 128) {
#pragma unroll
        for (int it = 0; it < 2; ++it) {
            const int jj = lane + it * 64;
            if (jj < deg) {
                const int sn = col[rs + jj];
                lsw[jj] = sn;
                const float e = leaky(s[sn] + dn);
                lexw[jj] = e;
                mx = fmaxf(mx, e);
            }
        }
#pragma unroll
        for (int off = 1; off < 64; off <<= 1) mx = fmaxf(mx, __shfl_xor(mx, off));
#pragma unroll
        for (int it = 0; it < 2; ++it) {
            const int jj = lane + it * 64;
            if (jj < deg) {
                const float ex = __expf(lexw[jj] - mx);
                lexw[jj] = ex;
                dsum += ex;
            }
        }
        wave_fence();
        int jj = 0;
        for (; jj + 4 <= deg; jj += 4) {
            const int sn0 = lsw[jj], sn1 = lsw[jj + 1];
            const int sn2 = lsw[jj + 2], sn3 = lsw[jj + 3];
            const float e0 = lexw[jj], e1 = lexw[jj + 1];
            const float e2 = lexw[jj + 2], e3 = lexw[jj + 3];
            const ushort2 hv0 = *(const ushort2*)&h[(size_t)sn0 * 128 + lane * 2];
            const ushort2 hv1 = *(const ushort2*)&h[(size_t)sn1 * 128 + lane * 2];
            const ushort2 hv2 = *(const ushort2*)&h[(size_t)sn2 * 128 + lane * 2];
            const ushort2 hv3 = *(const ushort2*)&h[(size_t)sn3 * 128 + lane * 2];
            acc0 = fmaf(e0, bf2f(hv0.x), acc0); acc1 = fmaf(e0, bf2f(hv0.y), acc1);
            acc0 = fmaf(e1, bf2f(hv1.x), acc0); acc1 = fmaf(e1, bf2f(hv1.y), acc1);
            acc0 = fmaf(e2, bf2f(hv2.x), acc0); acc1 = fmaf(e2, bf2f(hv2.y), acc1);
            acc0 = fmaf(e3, bf2f(hv3.x), acc0); acc1 = fmaf(e3, bf2f(hv3.y), acc1);
        }
        for (; jj < deg; ++jj) {
            const int sn = lsw[jj];
            const float ex = lexw[jj];
            const ushort2 hv = *(const ushort2*)&h[(size_t)sn * 128 + lane * 2];
            acc0 = fmaf(ex, bf2f(hv.x), acc0);
            acc1 = fmaf(ex, bf2f(hv.y), acc1);
        }
    } else {
        for (int j = rs + lane; j < re; j += 64) {
            mx = fmaxf(mx, leaky(s[col[j]] + dn));
        }
#pragma unroll
        for (int off = 1; off < 64; off <<= 1) mx = fmaxf(mx, __shfl_xor(mx, off));
        for (int c0 = rs; c0 < re; c0 += 128) {
            const int cend = min(re, c0 + 128);
#pragma unroll
            for (int it = 0; it < 2; ++it) {
                const int j = c0 + lane + it * 64;
                if (j < cend) {
                    const int sn = col[j];
                    const int jj = j - c0;
                    lsw[jj] = sn;
                    const float ex = __expf(leaky(s[sn] + dn) - mx);
                    lexw[jj] = ex;
                    dsum += ex;
                }
            }
            wave_fence();
            const int cnum = cend - c0;
            for (int jj = 0; jj < cnum; ++jj) {
                const int sn = lsw[jj];
                const float ex = lexw[jj];
                const ushort2 hv = *(const ushort2*)&h[(size_t)sn * 128 + lane * 2];
                acc0 = fmaf(ex, bf2f(hv.x), acc0);
                acc1 = fmaf(ex, bf2f(hv.y), acc1);
            }
            wave_fence();
        }
    }
#pragma unroll
    for (int off = 1; off < 64; off <<= 1) dsum += __shfl_xor(dsum, off);
    const float inv = 1.f / (dsum + 1e-16f);
    const int c = lane * 2;
    float2 o = make_float2(acc0 * inv + bias[c], acc1 * inv + bias[c + 1]);
    *(float2*)&y[(size_t)n * 128 + c] = o;
}

// ---------- fused BatchNorm stats ----------
__global__ __launch_bounds__(256) void bn_stats_fused(
    const float* __restrict__ y, float* __restrict__ partial,
    const float* __restrict__ gamma, const float* __restrict__ beta,
    float* __restrict__ stats, unsigned* __restrict__ ticket) {
    const int b = blockIdx.x, t = threadIdx.x;
    const int c = t & 127;
    float sum = 0.f, sq = 0.f;
    for (int r = b * 2 + (t >> 7); r < N_NODES; r += 512) {
        const float v = y[(size_t)r * 128 + c];
        sum += v;
        sq += v * v;
    }
    __shared__ float s1[256], s2[256];
    s1[t] = sum; s2[t] = sq;
    __syncthreads();
    if (t < 128) {
        partial[(size_t)b * 256 + c] = s1[t] + s1[t + 128];
        partial[(size_t)b * 256 + 128 + c] = s2[t] + s2[t + 128];
    }
    __threadfence();
    __shared__ unsigned rank;
    if (t == 0) rank = atomicAdd(ticket, 1u);
    __syncthreads();
    if (rank == 255u) {
        __threadfence();
        if (t < 128) {
            float S = 0.f, Q = 0.f;
            for (int b2 = 0; b2 < 256; ++b2) {
                S += partial[(size_t)b2 * 256 + t];
                Q += partial[(size_t)b2 * 256 + 128 + t];
            }
            const float mu = S / (float)N_NODES;
            const float var = Q / (float)N_NODES - mu * mu;
            const float sc = gamma[t] * rsqrtf(var + EPS_BN);
            stats[t] = sc;
            stats[128 + t] = beta[t] - mu * sc;
        }
    }
}

// final BN -> fp32 d_out (no relu)
__global__ void bn_apply_out(const float* __restrict__ y,
                             const float* __restrict__ stats,
                             float* __restrict__ out) {
    const int i = blockIdx.x * blockDim.x + threadIdx.x;
    if (i < N_NODES * 128) {
        const int c = i & 127;
        out[i] = y[i] * stats[c] + stats[128 + c];
    }
}

// ---------- launch ----------
extern "C" void kernel_launch(void* const* d_in, const int* in_sizes, int n_in,
                              void* d_out, int out_size, void* d_ws, size_t ws_size,
                              hipStream_t stream) {
    const float* x = (const float*)d_in[0];
    const int* ei = (const int*)d_in[1];
    const int E = in_sizes[1] / 2;
    const int ET = E + N_NODES;

    const float* W[3]    = {(const float*)d_in[2], (const float*)d_in[8],  (const float*)d_in[14]};
    const float* ASRC[3] = {(const float*)d_in[3], (const float*)d_in[9],  (const float*)d_in[15]};
    const float* ADST[3] = {(const float*)d_in[4], (const float*)d_in[10], (const float*)d_in[16]};
    const float* BIAS[3] = {(const float*)d_in[5], (const float*)d_in[11], (const float*)d_in[17]};
    const float* GAM[3]  = {(const float*)d_in[6], (const float*)d_in[12], (const float*)d_in[18]};
    const float* BET[3]  = {(const float*)d_in[7], (const float*)d_in[13], (const float*)d_in[19]};

    char* base = (char*)d_ws;
    auto alloc = [&](size_t bytes) {
        char* p = base;
        base += (bytes + 255) & ~(size_t)255;
        return p;
    };
    ushort* hbf    = (ushort*)alloc((size_t)M_PAD * 512 * 2);
    ushort* Xbf    = (ushort*)alloc((size_t)M_PAD * 256 * 2);
    ushort* Wt0    = (ushort*)alloc((size_t)512 * 256 * 2);
    ushort* Wt1    = (ushort*)alloc((size_t)512 * 128 * 2);
    ushort* Wt2    = (ushort*)alloc((size_t)128 * 128 * 2);
    float*  y      = (float*)alloc((size_t)M_PAD * 128 * 4);
    float*  s      = (float*)alloc((size_t)N_NODES * 4 * 4);
    float*  dsc    = (float*)alloc((size_t)N_NODES * 4 * 4);
    int*    rowptr = (int*)alloc((size_t)(N_NODES + 1) * 4);
    int*    col    = (int*)alloc((size_t)ET * 4);
    int*    cnt    = (int*)alloc((size_t)(N_NODES + 8) * 4);   // +8: bn tickets
    int*    incl   = (int*)alloc((size_t)N_NODES * 4);
    int*    bsum   = (int*)alloc((size_t)64 * 4);
    float*  partial = (float*)alloc((size_t)256 * 256 * 4);
    float*  stats   = (float*)alloc((size_t)256 * 4);
    if ((size_t)(base - (char*)d_ws) > ws_size) return;

    unsigned* tickets = (unsigned*)(cnt + N_NODES);

    const int eb = (ET + 255) / 256;
    const int nScanB = (N_NODES + 1023) / 1024;

    // --- CSR build (hist fused into prep) ---
    hipMemsetAsync(cnt, 0, (size_t)(N_NODES + 8) * 4, stream);
    prep<<<(M_PAD * 256 / 4 + 255) / 256, 256, 0, stream>>>(
        x, Xbf, W[0], W[1], W[2], Wt0, Wt1, Wt2, ei, E, cnt);
    scan_phase1<<<nScanB, 256, 0, stream>>>(cnt, incl, bsum, N_NODES);
    scan_phase3b<<<(N_NODES + 255) / 256, 256, 0, stream>>>(incl, bsum, rowptr, cnt, N_NODES);
    edge_scatter<<<eb, 256, 0, stream>>>(ei, E, cnt, col);

    // ---- layer 0 (H=4, K=256) ----
    {
        dim3 g0(512 / 128, M_PAD / 128);
        gemm_fused<false><<<g0, 256, 0, stream>>>(
            Xbf, nullptr, nullptr, Wt0, hbf, 256, 512, 4, ASRC[0], ADST[0], s, dsc);
        aggregate4<<<N_NODES / 4, 256, 0, stream>>>(hbf, s, dsc, rowptr, col, BIAS[0], y);
        bn_stats_fused<<<256, 256, 0, stream>>>(y, partial, GAM[0], BET[0], stats, tickets + 0);
    }
    // ---- layer 1 (H=4, K=128, BN+ReLU fused into gemm prologue) ----
    {
        dim3 g1(512 / 128, M_PAD / 128);
        gemm_fused<true><<<g1, 256, 0, stream>>>(
            nullptr, y, stats, Wt1, hbf, 128, 512, 4, ASRC[1], ADST[1], s, dsc);
        aggregate4<<<N_NODES / 4, 256, 0, stream>>>(hbf, s, dsc, rowptr, col, BIAS[1], y);
        bn_stats_fused<<<256, 256, 0, stream>>>(y, partial, GAM[1], BET[1], stats, tickets + 1);
    }
    // ---- layer 2 (H=1, K=128) ----
    {
        dim3 g2(128 / 128, M_PAD / 128);
        gemm_fused<true><<<g2, 256, 0, stream>>>(
            nullptr, y, stats, Wt2, hbf, 128, 128, 1, ASRC[2], ADST[2], s, dsc);
        aggregate1<<<N_NODES / 4, 256, 0, stream>>>(hbf, s, dsc, rowptr, col, BIAS[2], y);
        bn_stats_fused<<<256, 256, 0, stream>>>(y, partial, GAM[2], BET[2], stats, tickets + 2);
    }
    bn_apply_out<<<(N_NODES * 128 + 255) / 256, 256, 0, stream>>>(y, stats, (float*)d_out);
}